// Round 3
// baseline (3666.895 us; speedup 1.0000x reference)
//
#include <hip/hip_runtime.h>
#include <math.h>

// ---------------------------------------------------------------------------
// Decoder: out[b,t,n] = V - 2 * sum_k v_k / (Ep[b,n,k]*Eq[t,k] + 1)
//   Ep = exp2(c*enc@Wref^T), Eq = exp2(c*q_t), c = 2*log2(e)  (tanh identity)
//   hid_t is batch-independent (LSTM input == previous hidden, h0 = 0).
// ---------------------------------------------------------------------------

#define LOG2E     1.4426950408889634f
#define TWO_LOG2E 2.8853900817779268f

#if __has_builtin(__builtin_amdgcn_exp2f)
__device__ __forceinline__ float fast_exp2(float x) { return __builtin_amdgcn_exp2f(x); }
#else
__device__ __forceinline__ float fast_exp2(float x) { return exp2f(x); }
#endif

#if __has_builtin(__builtin_amdgcn_rcpf)
__device__ __forceinline__ float fast_rcp(float x) { return __builtin_amdgcn_rcpf(x); }
#else
__device__ __forceinline__ float fast_rcp(float x) { return 1.0f / x; }
#endif

#if __has_builtin(__builtin_amdgcn_sdot4)
__device__ __forceinline__ int sdot4(int a, int b, int c) {
  return __builtin_amdgcn_sdot4(a, b, c, false);
}
#else
__device__ __forceinline__ int sdot4(int a, int b, int c) {
  c += (int)(signed char)(a)       * (int)(signed char)(b);
  c += (int)(signed char)(a >> 8)  * (int)(signed char)(b >> 8);
  c += (int)(signed char)(a >> 16) * (int)(signed char)(b >> 16);
  c += (int)(signed char)(a >> 24) * (int)(signed char)(b >> 24);
  return c;
}
#endif

typedef _Float16 half4v __attribute__((ext_vector_type(4)));

// ---- ws layout (bytes) ----
// 0       : wpack  int32[65536]
// 262144  : bsum   float[1024]
// 266240  : vsum   float[1]
// 266496  : hid    float[512*256]
// 790784  : eqs    float[512*256] (Eq = exp2(clamped c*q))

// ---------------------------------------------------------------------------
__global__ void prep_kernel(const float* __restrict__ Wih, const float* __restrict__ Whh,
                            const float* __restrict__ bih, const float* __restrict__ bhh,
                            const float* __restrict__ v,
                            int* __restrict__ wpack, float* __restrict__ bsum,
                            float* __restrict__ vsum) {
  const int bid = blockIdx.x, tid = threadIdx.x;
  if (bid < 256) {
    const int idx = bid * 256 + tid;      // idx = i*1024 + g
    const int g  = idx & 1023;
    const int h0 = (idx >> 10) << 2;
    unsigned pk = 0u;
#pragma unroll
    for (int b = 0; b < 4; ++b) {
      float val = Wih[g * 256 + h0 + b] + Whh[g * 256 + h0 + b];
      int qi = (int)rintf(val * (127.0f / 0.125f));   // |W_ih+W_hh| < 0.125 strictly
      qi = qi > 127 ? 127 : (qi < -127 ? -127 : qi);
      pk |= ((unsigned)(qi & 255)) << (8 * b);
    }
    wpack[idx] = (int)pk;
  } else if (bid < 260) {
    const int g = (bid - 256) * 256 + tid;
    bsum[g] = bih[g] + bhh[g];
  } else {
    __shared__ float red[256];
    red[tid] = v[tid];
    __syncthreads();
    for (int s = 128; s > 0; s >>= 1) {
      if (tid < s) red[tid] += red[tid + s];
      __syncthreads();
    }
    if (tid == 0) vsum[0] = red[0];
  }
}

// ---------------------------------------------------------------------------
// Single-block serial LSTM. Weights int8-resident in VGPRs (64 dwords/thread),
// hid carried as two-level int8 (hid ~= (254*b1 + b2) / (127*254), err <= 1.5e-5).
// ---------------------------------------------------------------------------
__global__ __launch_bounds__(1024, 1) void lstm_kernel(
    const int* __restrict__ wpack, const float* __restrict__ bsum,
    float* __restrict__ hid_all) {
  __shared__ int4  h1v[16];
  __shared__ int4  h2v[16];
  __shared__ float gates[1024];
  const int tid = threadIdx.x;

  int w[64];
#pragma unroll
  for (int i = 0; i < 64; ++i) w[i] = wpack[i * 1024 + tid];
  const float bias = bsum[tid];
  float cell = 0.0f;

  if (tid < 16) { h1v[tid] = make_int4(0, 0, 0, 0); h2v[tid] = make_int4(0, 0, 0, 0); }
  __syncthreads();

  const float SC = 0.125f / (127.0f * 127.0f * 254.0f);  // s_w * s_h2

  for (int t = 0; t < 512; ++t) {
    int a1 = 0, a2 = 0;
#pragma unroll
    for (int i = 0; i < 16; ++i) {
      const int4 x1 = h1v[i];
      const int4 x2 = h2v[i];
      a1 = sdot4(w[4 * i + 0], x1.x, a1); a2 = sdot4(w[4 * i + 0], x2.x, a2);
      a1 = sdot4(w[4 * i + 1], x1.y, a1); a2 = sdot4(w[4 * i + 1], x2.y, a2);
      a1 = sdot4(w[4 * i + 2], x1.z, a1); a2 = sdot4(w[4 * i + 2], x2.z, a2);
      a1 = sdot4(w[4 * i + 3], x1.w, a1); a2 = sdot4(w[4 * i + 3], x2.w, a2);
    }
    const float gf = fmaf((float)(254 * a1 + a2), SC, bias);
    gates[tid] = gf;
    __syncthreads();

    if (tid < 256) {
      const float gi  = gates[tid];
      const float gfr = gates[256 + tid];
      const float gg  = gates[512 + tid];
      const float go  = gates[768 + tid];
      const float si = fast_rcp(1.0f + fast_exp2(-LOG2E * gi));
      const float sf = fast_rcp(1.0f + fast_exp2(-LOG2E * gfr));
      const float so = fast_rcp(1.0f + fast_exp2(-LOG2E * go));
      const float tg = 1.0f - 2.0f * fast_rcp(fast_exp2(TWO_LOG2E * gg) + 1.0f);
      cell = sf * cell + si * tg;
      const float tc = 1.0f - 2.0f * fast_rcp(fast_exp2(TWO_LOG2E * cell) + 1.0f);
      const float hv = so * tc;
      hid_all[t * 256 + tid] = hv;

      int b1 = (int)rintf(hv * 127.0f);
      b1 = b1 > 127 ? 127 : (b1 < -127 ? -127 : b1);
      const float r = fmaf((float)b1, -1.0f / 127.0f, hv);
      int b2 = (int)rintf(r * (127.0f * 254.0f));
      b2 = b2 > 127 ? 127 : (b2 < -127 ? -127 : b2);
      ((signed char*)h1v)[tid] = (signed char)b1;
      ((signed char*)h2v)[tid] = (signed char)b2;
    }
    __syncthreads();
  }
}

// ---------------------------------------------------------------------------
// q-projection; writes Eq = exp2(clamp(c * hid@Wq^T, +-15))
// ---------------------------------------------------------------------------
__global__ __launch_bounds__(256) void qproj_kernel(
    const float* __restrict__ hid_all, const float* __restrict__ Wq,
    float* __restrict__ eqs) {
  __shared__ float hrow[256];
  const int t = blockIdx.x, k = threadIdx.x;
  hrow[k] = hid_all[t * 256 + k];
  __syncthreads();
  const float* wr = Wq + k * 256;
  float acc = 0.0f;
#pragma unroll 8
  for (int h = 0; h < 256; h += 4) {
    const float4 w4 = *(const float4*)(wr + h);
    acc = fmaf(w4.x, hrow[h + 0], acc);
    acc = fmaf(w4.y, hrow[h + 1], acc);
    acc = fmaf(w4.z, hrow[h + 2], acc);
    acc = fmaf(w4.w, hrow[h + 3], acc);
  }
  float x = acc * TWO_LOG2E;
  x = fminf(fmaxf(x, -15.0f), 15.0f);
  eqs[t * 256 + k] = fast_exp2(x);
}

// ---------------------------------------------------------------------------
// Fused main kernel. Phase 1: Ep tile (fp16) in LDS. Phase 2: all 512 t with
// 4-way common-denominator rcp; Eq row staged per-wave in double-buffered LDS
// (broadcast ds_read_b128, imm offsets), v staged per-block. No VMEM and no
// address VALU in the inner loop.
// ---------------------------------------------------------------------------
#define EPSTRIDE 276   // halves per row (552 B): bank-rotating, 2-way (free)

__global__ __launch_bounds__(512) void main_kernel(
    const float* __restrict__ enc, const float* __restrict__ Wref,
    const float* __restrict__ Eqs, const float* __restrict__ v,
    const float* __restrict__ vsum, float* __restrict__ out) {
  __shared__ _Float16 ep[64 * EPSTRIDE];      // 35328 B
  __shared__ float    eqstage[8 * 2 * 256];   // 16384 B: [wave][buf][k]
  __shared__ float    vlds[256];              // 1024 B
  const int tid = threadIdx.x;
  const int b   = blockIdx.y;
  const int n0  = blockIdx.x * 64;

  if (tid < 256) vlds[tid] = v[tid];

  // ---- phase 1: Ep[n][k] = exp2(clamp(c * dot(enc[b][n0+n], Wref[k]))) ----
  {
    const int kk = tid & 255;
    const int hh = tid >> 8;                 // 0 or 1 -> n subsets
    const float* wr = Wref + kk * 256;
    const float* er = enc + ((size_t)(b * 512 + n0 + hh * 32)) * 256;
    float acc[32];
#pragma unroll
    for (int i = 0; i < 32; ++i) acc[i] = 0.0f;
    for (int h4 = 0; h4 < 256; h4 += 4) {
      const float4 w4 = *(const float4*)(wr + h4);
#pragma unroll
      for (int n2 = 0; n2 < 32; ++n2) {
        const float4 e4 = *(const float4*)(er + n2 * 256 + h4);
        acc[n2] = fmaf(e4.x, w4.x, acc[n2]);
        acc[n2] = fmaf(e4.y, w4.y, acc[n2]);
        acc[n2] = fmaf(e4.z, w4.z, acc[n2]);
        acc[n2] = fmaf(e4.w, w4.w, acc[n2]);
      }
    }
#pragma unroll
    for (int n2 = 0; n2 < 32; ++n2) {
      const int n = hh * 32 + n2;
      float x = acc[n2] * TWO_LOG2E;
      x = fminf(fmaxf(x, -15.0f), 15.0f);
      ep[n * EPSTRIDE + kk] = (_Float16)fast_exp2(x);
    }
  }
  __syncthreads();

  // ---- phase 2 ----
  const int lane = tid & 63;
  const int wv   = __builtin_amdgcn_readfirstlane(tid >> 6);  // 0..7
  const float V  = vsum[0];
  const _Float16* rowp = ep + lane * EPSTRIDE;
  const float4*  vb    = (const float4*)vlds;
  float* outb = out + ((size_t)b * 512) * 512 + n0;
  float* mybuf = eqstage + wv * 512;          // two 256-float buffers

  // prologue: stage Eq row for t = wv into buf 0
  {
    float4 g = *(const float4*)(Eqs + wv * 256 + lane * 4);
    *(float4*)(mybuf + lane * 4) = g;
  }

  for (int i = 0; i < 64; ++i) {
    const int t = wv + i * 8;
    // prefetch next t's Eq row (hidden under compute below)
    float4 gnext;
    const int tn = (i < 63) ? (t + 8) : t;
    gnext = *(const float4*)(Eqs + tn * 256 + lane * 4);

    const float4* eb = (const float4*)(mybuf + (i & 1) * 256);
    float acc0 = 0.0f, acc1 = 0.0f;
#pragma unroll 8
    for (int c = 0; c < 64; ++c) {
      const half4v h  = *(const half4v*)(rowp + c * 4);  // ds_read_b64, imm ofs
      const float4 q4 = eb[c];                           // broadcast b128
      const float4 v4 = vb[c];                           // broadcast b128
      const float f0 = fmaf((float)h.x, q4.x, 1.0f);     // v_fma_mix_f32
      const float f1 = fmaf((float)h.y, q4.y, 1.0f);
      const float f2 = fmaf((float)h.z, q4.z, 1.0f);
      const float f3 = fmaf((float)h.w, q4.w, 1.0f);
      const float p01 = f0 * f1;
      const float p23 = f2 * f3;
      float n01 = v4.x * f1; n01 = fmaf(v4.y, f0, n01);
      float n23 = v4.z * f3; n23 = fmaf(v4.w, f2, n23);
      float nn  = n01 * p23; nn  = fmaf(n23, p01, nn);
      const float d = p01 * p23;
      if (c & 1) acc1 = fmaf(nn, fast_rcp(d), acc1);
      else       acc0 = fmaf(nn, fast_rcp(d), acc0);
    }
    outb[(size_t)t * 512 + lane] = fmaf(-2.0f, acc0 + acc1, V);

    // stage next row into the other buffer (in-order LDS pipe; WAR-safe)
    *(float4*)(mybuf + ((i + 1) & 1) * 256 + lane * 4) = gnext;
  }
}

// ---------------------------------------------------------------------------
extern "C" void kernel_launch(void* const* d_in, const int* in_sizes, int n_in,
                              void* d_out, int out_size, void* d_ws, size_t ws_size,
                              hipStream_t stream) {
  const float* enc  = (const float*)d_in[0];
  const float* Wih  = (const float*)d_in[1];
  const float* Whh  = (const float*)d_in[2];
  const float* bih  = (const float*)d_in[3];
  const float* bhh  = (const float*)d_in[4];
  const float* Wref = (const float*)d_in[5];
  const float* Wq   = (const float*)d_in[6];
  const float* v    = (const float*)d_in[7];
  float* out = (float*)d_out;

  char* ws = (char*)d_ws;
  int*   wpack = (int*)(ws + 0);
  float* bsum  = (float*)(ws + 262144);
  float* vsum  = (float*)(ws + 266240);
  float* hid   = (float*)(ws + 266496);
  float* eqs   = (float*)(ws + 790784);

  prep_kernel<<<261, 256, 0, stream>>>(Wih, Whh, bih, bhh, v, wpack, bsum, vsum);
  lstm_kernel<<<1, 1024, 0, stream>>>(wpack, bsum, hid);
  qproj_kernel<<<512, 256, 0, stream>>>(hid, Wq, eqs);
  dim3 grid(8, 256);
  main_kernel<<<grid, 512, 0, stream>>>(enc, Wref, eqs, v, vsum, out);
}

// Round 4
// 2996.772 us; speedup vs baseline: 1.2236x; 1.2236x over previous
//
#include <hip/hip_runtime.h>
#include <math.h>

// ---------------------------------------------------------------------------
// Decoder: out[b,t,n] = V - 2 * sum_k v_k / (Ep[b,n,k]*Eq[t,k] + 1)
//   Ep = exp2(c*enc@Wref^T) (f16, VGPR-resident), Eq = exp2(c*q_t)
//   hid_t is batch-independent (LSTM input == previous hidden, h0 = 0).
// ---------------------------------------------------------------------------

#define LOG2E     1.4426950408889634f
#define TWO_LOG2E 2.8853900817779268f

#if __has_builtin(__builtin_amdgcn_exp2f)
__device__ __forceinline__ float fast_exp2(float x) { return __builtin_amdgcn_exp2f(x); }
#else
__device__ __forceinline__ float fast_exp2(float x) { return exp2f(x); }
#endif

#if __has_builtin(__builtin_amdgcn_rcpf)
__device__ __forceinline__ float fast_rcp(float x) { return __builtin_amdgcn_rcpf(x); }
#else
__device__ __forceinline__ float fast_rcp(float x) { return 1.0f / x; }
#endif

#if __has_builtin(__builtin_amdgcn_sdot4)
__device__ __forceinline__ int sdot4(int a, int b, int c) {
  return __builtin_amdgcn_sdot4(a, b, c, false);
}
#else
__device__ __forceinline__ int sdot4(int a, int b, int c) {
  c += (int)(signed char)(a)       * (int)(signed char)(b);
  c += (int)(signed char)(a >> 8)  * (int)(signed char)(b >> 8);
  c += (int)(signed char)(a >> 16) * (int)(signed char)(b >> 16);
  c += (int)(signed char)(a >> 24) * (int)(signed char)(b >> 24);
  return c;
}
#endif

// f = f16(lo/hi half of hreg) * q + 1.0   -- forced v_fma_mix_f32
__device__ __forceinline__ float fmix_lo(unsigned hreg, float q) {
  float r;
  asm("v_fma_mix_f32 %0, %1, %2, 1.0 op_sel:[0,0,0] op_sel_hi:[1,0,0]"
      : "=v"(r) : "v"(hreg), "v"(q));
  return r;
}
__device__ __forceinline__ float fmix_hi(unsigned hreg, float q) {
  float r;
  asm("v_fma_mix_f32 %0, %1, %2, 1.0 op_sel:[1,0,0] op_sel_hi:[1,0,0]"
      : "=v"(r) : "v"(hreg), "v"(q));
  return r;
}

// ---- ws layout (bytes) ----
// 0       : wpack  int32[65536]
// 262144  : bsum   float[1024]
// 266240  : vsum   float[1]
// 266496  : hid    float[512*256]
// 790784  : eqs    float[512*256] (Eq = exp2(clamped c*q))

// ---------------------------------------------------------------------------
__global__ void prep_kernel(const float* __restrict__ Wih, const float* __restrict__ Whh,
                            const float* __restrict__ bih, const float* __restrict__ bhh,
                            const float* __restrict__ v,
                            int* __restrict__ wpack, float* __restrict__ bsum,
                            float* __restrict__ vsum) {
  const int bid = blockIdx.x, tid = threadIdx.x;
  if (bid < 256) {
    const int idx = bid * 256 + tid;      // idx = i*1024 + g
    const int g  = idx & 1023;
    const int h0 = (idx >> 10) << 2;
    unsigned pk = 0u;
#pragma unroll
    for (int b = 0; b < 4; ++b) {
      float val = Wih[g * 256 + h0 + b] + Whh[g * 256 + h0 + b];
      int qi = (int)rintf(val * (127.0f / 0.125f));   // |W_ih+W_hh| < 0.125 strictly
      qi = qi > 127 ? 127 : (qi < -127 ? -127 : qi);
      pk |= ((unsigned)(qi & 255)) << (8 * b);
    }
    wpack[idx] = (int)pk;
  } else if (bid < 260) {
    const int g = (bid - 256) * 256 + tid;
    bsum[g] = bih[g] + bhh[g];
  } else {
    __shared__ float red[256];
    red[tid] = v[tid];
    __syncthreads();
    for (int s = 128; s > 0; s >>= 1) {
      if (tid < s) red[tid] += red[tid + s];
      __syncthreads();
    }
    if (tid == 0) vsum[0] = red[0];
  }
}

// ---------------------------------------------------------------------------
// Single-block serial LSTM. Weights int8-resident in VGPRs (64 dwords/thread),
// hid carried as two-level int8 (hid ~= (254*b1 + b2) / (127*254), err <= 1.5e-5).
// ---------------------------------------------------------------------------
__global__ __launch_bounds__(1024, 1) void lstm_kernel(
    const int* __restrict__ wpack, const float* __restrict__ bsum,
    float* __restrict__ hid_all) {
  __shared__ int4  h1v[16];
  __shared__ int4  h2v[16];
  __shared__ float gates[1024];
  const int tid = threadIdx.x;

  int w[64];
#pragma unroll
  for (int i = 0; i < 64; ++i) w[i] = wpack[i * 1024 + tid];
  const float bias = bsum[tid];
  float cell = 0.0f;

  if (tid < 16) { h1v[tid] = make_int4(0, 0, 0, 0); h2v[tid] = make_int4(0, 0, 0, 0); }
  __syncthreads();

  const float SC = 0.125f / (127.0f * 127.0f * 254.0f);  // s_w * s_h2

  for (int t = 0; t < 512; ++t) {
    int a1 = 0, a2 = 0;
#pragma unroll
    for (int i = 0; i < 16; ++i) {
      const int4 x1 = h1v[i];
      const int4 x2 = h2v[i];
      a1 = sdot4(w[4 * i + 0], x1.x, a1); a2 = sdot4(w[4 * i + 0], x2.x, a2);
      a1 = sdot4(w[4 * i + 1], x1.y, a1); a2 = sdot4(w[4 * i + 1], x2.y, a2);
      a1 = sdot4(w[4 * i + 2], x1.z, a1); a2 = sdot4(w[4 * i + 2], x2.z, a2);
      a1 = sdot4(w[4 * i + 3], x1.w, a1); a2 = sdot4(w[4 * i + 3], x2.w, a2);
    }
    const float gf = fmaf((float)(254 * a1 + a2), SC, bias);
    gates[tid] = gf;
    __syncthreads();

    if (tid < 256) {
      const float gi  = gates[tid];
      const float gfr = gates[256 + tid];
      const float gg  = gates[512 + tid];
      const float go  = gates[768 + tid];
      const float si = fast_rcp(1.0f + fast_exp2(-LOG2E * gi));
      const float sf = fast_rcp(1.0f + fast_exp2(-LOG2E * gfr));
      const float so = fast_rcp(1.0f + fast_exp2(-LOG2E * go));
      const float tg = 1.0f - 2.0f * fast_rcp(fast_exp2(TWO_LOG2E * gg) + 1.0f);
      cell = sf * cell + si * tg;
      const float tc = 1.0f - 2.0f * fast_rcp(fast_exp2(TWO_LOG2E * cell) + 1.0f);
      const float hv = so * tc;
      hid_all[t * 256 + tid] = hv;

      int b1 = (int)rintf(hv * 127.0f);
      b1 = b1 > 127 ? 127 : (b1 < -127 ? -127 : b1);
      const float r = fmaf((float)b1, -1.0f / 127.0f, hv);
      int b2 = (int)rintf(r * (127.0f * 254.0f));
      b2 = b2 > 127 ? 127 : (b2 < -127 ? -127 : b2);
      ((signed char*)h1v)[tid] = (signed char)b1;
      ((signed char*)h2v)[tid] = (signed char)b2;
    }
    __syncthreads();
  }
}

// ---------------------------------------------------------------------------
// q-projection; writes Eq = exp2(clamp(c * hid@Wq^T, +-15))
// ---------------------------------------------------------------------------
__global__ __launch_bounds__(256) void qproj_kernel(
    const float* __restrict__ hid_all, const float* __restrict__ Wq,
    float* __restrict__ eqs) {
  __shared__ float hrow[256];
  const int t = blockIdx.x, k = threadIdx.x;
  hrow[k] = hid_all[t * 256 + k];
  __syncthreads();
  const float* wr = Wq + k * 256;
  float acc = 0.0f;
#pragma unroll 8
  for (int h = 0; h < 256; h += 4) {
    const float4 w4 = *(const float4*)(wr + h);
    acc = fmaf(w4.x, hrow[h + 0], acc);
    acc = fmaf(w4.y, hrow[h + 1], acc);
    acc = fmaf(w4.z, hrow[h + 2], acc);
    acc = fmaf(w4.w, hrow[h + 3], acc);
  }
  float x = acc * TWO_LOG2E;
  x = fminf(fmaxf(x, -15.0f), 15.0f);
  eqs[t * 256 + k] = fast_exp2(x);
}

// ---------------------------------------------------------------------------
// Fused main kernel, Ep-in-VGPR version.
// grid = (16 n-tiles of 32, 256 b), 512 threads.
// Phase 1: 32n x 256k GEMM -> Ep f16 tile in LDS (linear, transient).
// Then each lane (n = lane&31, khalf = lane>>5) loads its 128-k Ep slice into
// 64 VGPRs. Phase 2: per t, 32 4-elem groups, all operands VGPR or broadcast
// LDS b128; v_fma_mix_f32 forced via asm; shfl_xor(32) merges k-halves.
// ---------------------------------------------------------------------------
#define EPROW 260   // halves per row (520 B)

__global__ __launch_bounds__(512) void main_kernel(
    const float* __restrict__ enc, const float* __restrict__ Wref,
    const float* __restrict__ Eqs, const float* __restrict__ v,
    const float* __restrict__ vsum, float* __restrict__ out) {
  __shared__ _Float16 eplds[32 * EPROW];      // 16640 B (transient)
  __shared__ float    eqstage[8 * 2 * 256];   // 16384 B: [wave][buf][k]
  __shared__ float    vlds[256];              // 1024 B
  const int tid = threadIdx.x;
  const int b   = blockIdx.y;
  const int n0  = blockIdx.x * 32;

  if (tid < 256) vlds[tid] = v[tid];

  // ---- phase 1: Ep[n][k] = exp2(clamp(c * dot(enc[b][n0+n], Wref[k]))) ----
  {
    const int kk = tid & 255;
    const int hh = tid >> 8;                 // n-half: rows hh*16 .. hh*16+15
    const float* wr = Wref + kk * 256;
    const float* er = enc + ((size_t)(b * 512 + n0 + hh * 16)) * 256;
    float acc[16];
#pragma unroll
    for (int i = 0; i < 16; ++i) acc[i] = 0.0f;
    for (int h4 = 0; h4 < 256; h4 += 4) {
      const float4 w4 = *(const float4*)(wr + h4);
#pragma unroll
      for (int n2 = 0; n2 < 16; ++n2) {
        const float4 e4 = *(const float4*)(er + n2 * 256 + h4);
        acc[n2] = fmaf(e4.x, w4.x, acc[n2]);
        acc[n2] = fmaf(e4.y, w4.y, acc[n2]);
        acc[n2] = fmaf(e4.z, w4.z, acc[n2]);
        acc[n2] = fmaf(e4.w, w4.w, acc[n2]);
      }
    }
#pragma unroll
    for (int n2 = 0; n2 < 16; ++n2) {
      const int n = hh * 16 + n2;
      float x = acc[n2] * TWO_LOG2E;
      x = fminf(fmaxf(x, -15.0f), 15.0f);
      eplds[n * EPROW + kk] = (_Float16)fast_exp2(x);
    }
  }
  __syncthreads();

  // ---- load Ep slice into VGPRs: lane (n, half) holds k = half*128..+127 ----
  const int lane = tid & 63;
  const int wv   = __builtin_amdgcn_readfirstlane(tid >> 6);  // 0..7
  const int nn_  = lane & 31;
  const int half = lane >> 5;
  unsigned myEp[64];
  {
    const _Float16* src = eplds + nn_ * EPROW + half * 128;
#pragma unroll
    for (int j = 0; j < 32; ++j) {
      const uint2 d = *(const uint2*)(src + j * 4);
      myEp[2 * j]     = d.x;
      myEp[2 * j + 1] = d.y;
    }
  }

  // ---- phase 2 ----
  const float V = vsum[0];
  float* outb = out + ((size_t)b * 512) * 512 + n0;
  float* mybuf = eqstage + wv * 512;          // two 256-float buffers
  const float4* vbq = (const float4*)vlds + half * 32;

  // prologue: stage Eq row for t = wv into buf 0
  {
    float4 g = *(const float4*)(Eqs + wv * 256 + lane * 4);
    *(float4*)(mybuf + lane * 4) = g;
  }

  for (int i = 0; i < 64; ++i) {
    const int t = wv + i * 8;
    // prefetch next t's Eq row (consumed at the bottom)
    const int tn = (i < 63) ? (t + 8) : t;
    const float4 gnext = *(const float4*)(Eqs + tn * 256 + lane * 4);

    const float4* ebq = (const float4*)(mybuf + (i & 1) * 256) + half * 32;
    float acc0 = 0.0f, acc1 = 0.0f;
#pragma unroll
    for (int c = 0; c < 32; ++c) {
      const float4 q4 = ebq[c];                      // broadcast b128 (2-addr)
      const float4 v4 = vbq[c];                      // broadcast b128 (2-addr)
      const float f0 = fmix_lo(myEp[2 * c],     q4.x);
      const float f1 = fmix_hi(myEp[2 * c],     q4.y);
      const float f2 = fmix_lo(myEp[2 * c + 1], q4.z);
      const float f3 = fmix_hi(myEp[2 * c + 1], q4.w);
      const float p01 = f0 * f1;
      const float p23 = f2 * f3;
      float n01 = v4.x * f1; n01 = fmaf(v4.y, f0, n01);
      float n23 = v4.z * f3; n23 = fmaf(v4.w, f2, n23);
      float nn  = n01 * p23; nn  = fmaf(n23, p01, nn);
      const float d = p01 * p23;
      if (c & 1) acc1 = fmaf(nn, fast_rcp(d), acc1);
      else       acc0 = fmaf(nn, fast_rcp(d), acc0);
    }
    float tot = acc0 + acc1;
    tot += __shfl_xor(tot, 32);
    if (half == 0) outb[(size_t)t * 512 + nn_] = fmaf(-2.0f, tot, V);

    // stage next row into the other buffer
    *(float4*)(mybuf + ((i + 1) & 1) * 256 + lane * 4) = gnext;
  }
}

// ---------------------------------------------------------------------------
extern "C" void kernel_launch(void* const* d_in, const int* in_sizes, int n_in,
                              void* d_out, int out_size, void* d_ws, size_t ws_size,
                              hipStream_t stream) {
  const float* enc  = (const float*)d_in[0];
  const float* Wih  = (const float*)d_in[1];
  const float* Whh  = (const float*)d_in[2];
  const float* bih  = (const float*)d_in[3];
  const float* bhh  = (const float*)d_in[4];
  const float* Wref = (const float*)d_in[5];
  const float* Wq   = (const float*)d_in[6];
  const float* v    = (const float*)d_in[7];
  float* out = (float*)d_out;

  char* ws = (char*)d_ws;
  int*   wpack = (int*)(ws + 0);
  float* bsum  = (float*)(ws + 262144);
  float* vsum  = (float*)(ws + 266240);
  float* hid   = (float*)(ws + 266496);
  float* eqs   = (float*)(ws + 790784);

  prep_kernel<<<261, 256, 0, stream>>>(Wih, Whh, bih, bhh, v, wpack, bsum, vsum);
  lstm_kernel<<<1, 1024, 0, stream>>>(wpack, bsum, hid);
  qproj_kernel<<<512, 256, 0, stream>>>(hid, Wq, eqs);
  dim3 grid(16, 256);
  main_kernel<<<grid, 512, 0, stream>>>(enc, Wref, eqs, v, vsum, out);
}